// Round 1
// baseline (792.046 us; speedup 1.0000x reference)
//
#include <hip/hip_runtime.h>

#define N_VAR   100000
#define N_CSTR  50000
#define NEDGE   1000000
#define DIM     64

// ---------------------------------------------------------------------------
// BN column stats: partial sum/sumsq per column, atomically accumulated into
// stats[0..63]=sum, stats[64..127]=sumsq.
// Block = 256 threads = 4 rows x 64 cols, grid-stride over rows.
// ---------------------------------------------------------------------------
__global__ __launch_bounds__(256) void bn_stats_k(const float* __restrict__ x, int n,
                                                  float* __restrict__ stats) {
  int c = threadIdx.x & 63;
  int rg = threadIdx.x >> 6;  // 0..3
  float s = 0.f, q = 0.f;
  for (int r = blockIdx.x * 4 + rg; r < n; r += gridDim.x * 4) {
    float v = x[r * DIM + c];
    s += v;
    q += v * v;
  }
  __shared__ float sb[256], qb[256];
  sb[threadIdx.x] = s;
  qb[threadIdx.x] = q;
  __syncthreads();
  if (rg == 0) {
    s = sb[c] + sb[c + 64] + sb[c + 128] + sb[c + 192];
    q = qb[c] + qb[c + 64] + qb[c + 128] + qb[c + 192];
    atomicAdd(&stats[c], s);
    atomicAdd(&stats[64 + c], q);
  }
}

// ---------------------------------------------------------------------------
// Finalize BN: a = gamma * rsqrt(var+eps), b = beta - mean*a.
// t<64: node (stats[0..127] -> ab[0..127]); t>=64: cstr (stats[128..] -> ab[128..]).
// ---------------------------------------------------------------------------
__global__ void bn_finalize_k(const float* __restrict__ stats,
                              const float* __restrict__ gn, const float* __restrict__ bn,
                              const float* __restrict__ gc, const float* __restrict__ bc,
                              float* __restrict__ ab) {
  int t = threadIdx.x;  // 0..127
  int c = t & 63;
  bool isC = t >= 64;
  const float* st = stats + (isC ? 128 : 0);
  float n = isC ? (float)N_CSTR : (float)N_VAR;
  float mean = st[c] / n;
  float var = st[64 + c] / n - mean * mean;
  float g = isC ? gc[c] : gn[c];
  float be = isC ? bc[c] : bn[c];
  float a = g * rsqrtf(var + 1e-5f);
  float b = be - mean * a;
  float* o = ab + (isC ? 128 : 0);
  o[c] = a;
  o[64 + c] = b;
}

// ---------------------------------------------------------------------------
// Edge scatter: one wave per edge, lane = column.
//   ssum_node[dst] += (cstr[src]*a_c+b_c) * w ; cnt_node[dst] += 1
//   ssum_cstr[src] += (var [dst]*a_n+b_n) * w ; cnt_cstr[src] += 1
// ---------------------------------------------------------------------------
__global__ __launch_bounds__(256) void edge_scatter_k(
    const float* __restrict__ vf, const float* __restrict__ cf,
    const int* __restrict__ esrc, const int* __restrict__ edst,
    const float* __restrict__ eattr, const float* __restrict__ ab,
    float* __restrict__ ssum_node, float* __restrict__ ssum_cstr,
    float* __restrict__ cnt_node, float* __restrict__ cnt_cstr) {
  int lane = threadIdx.x & 63;
  float a_n = ab[lane], b_n = ab[64 + lane];
  float a_c = ab[128 + lane], b_c = ab[192 + lane];
  int wave = (blockIdx.x * blockDim.x + threadIdx.x) >> 6;
  int nw = (gridDim.x * blockDim.x) >> 6;
  for (int e = wave; e < NEDGE; e += nw) {
    int s = esrc[e];
    int d = edst[e];
    float w = eattr[e];
    float xc = cf[s * DIM + lane] * a_c + b_c;
    atomicAdd(&ssum_node[d * DIM + lane], xc * w);
    float xn = vf[d * DIM + lane] * a_n + b_n;
    atomicAdd(&ssum_cstr[s * DIM + lane], xn * w);
    if (lane == 0) {
      atomicAdd(&cnt_node[d], 1.f);
      atomicAdd(&cnt_cstr[s], 1.f);
    }
  }
}

// ---------------------------------------------------------------------------
// Fused output: out[r][c] = relu( sum_k agg[r][k]*w_rel[c][k] + b_rel[c]
//                                + sum_k x[r][k]*w_root[c][k] + x[r][c] )
// where agg = ssum/max(cnt,1), x = raw*a+b.
// Block = 256 = 4 waves; each wave owns one row per iteration. Weights live
// in registers (lane c holds w_rel[c][:], w_root[c][:]); row vectors staged
// through LDS and read back as broadcast float4 (conflict-free).
// ---------------------------------------------------------------------------
__global__ __launch_bounds__(256) void out_k(
    const float* __restrict__ raw, const float* __restrict__ ssum,
    const float* __restrict__ cnt, const float* __restrict__ ab,
    const float* __restrict__ w_rel, const float* __restrict__ b_rel,
    const float* __restrict__ w_root, float* __restrict__ out, int n) {
  __shared__ float rowA[4][DIM];
  __shared__ float rowX[4][DIM];
  int lane = threadIdx.x & 63;
  int wv = threadIdx.x >> 6;
  float a = ab[lane], b = ab[64 + lane];
  float brel = b_rel[lane];
  float4 wr[16], wo[16];
#pragma unroll
  for (int i = 0; i < 16; ++i) {
    wr[i] = reinterpret_cast<const float4*>(w_rel + lane * DIM)[i];
    wo[i] = reinterpret_cast<const float4*>(w_root + lane * DIM)[i];
  }
  for (int r0 = blockIdx.x * 4; r0 < n; r0 += gridDim.x * 4) {
    int r = r0 + wv;
    float av = 0.f, xv = 0.f;
    if (r < n) {
      float inv = 1.f / fmaxf(cnt[r], 1.f);
      av = ssum[r * DIM + lane] * inv;
      xv = raw[r * DIM + lane] * a + b;
    }
    rowA[wv][lane] = av;
    rowX[wv][lane] = xv;
    __syncthreads();
    float acc0 = 0.f, acc1 = 0.f, acc2 = 0.f, acc3 = 0.f;
    const float4* RA = reinterpret_cast<const float4*>(rowA[wv]);
    const float4* RX = reinterpret_cast<const float4*>(rowX[wv]);
#pragma unroll
    for (int i = 0; i < 16; ++i) {
      float4 ra = RA[i];
      float4 rx = RX[i];
      acc0 += ra.x * wr[i].x + ra.y * wr[i].y;
      acc1 += ra.z * wr[i].z + ra.w * wr[i].w;
      acc2 += rx.x * wo[i].x + rx.y * wo[i].y;
      acc3 += rx.z * wo[i].z + rx.w * wo[i].w;
    }
    if (r < n) {
      out[r * DIM + lane] = fmaxf((acc0 + acc1) + brel + (acc2 + acc3) + xv, 0.f);
    }
    __syncthreads();
  }
}

// ---------------------------------------------------------------------------
// Workspace layout (floats):
//   [0)            ssum_node  6,400,000
//   [6,400,000)    ssum_cstr  3,200,000
//   [9,600,000)    cnt_node     100,000
//   [9,700,000)    cnt_cstr      50,000
//   [9,750,000)    stats            256   (node sum/sq, cstr sum/sq)
//   [9,750,256)    ab               256   (a_n, b_n, a_c, b_c)
// Total 9,750,512 floats = ~39 MB.
// ---------------------------------------------------------------------------
extern "C" void kernel_launch(void* const* d_in, const int* in_sizes, int n_in,
                              void* d_out, int out_size, void* d_ws, size_t ws_size,
                              hipStream_t stream) {
  const float* vf = (const float*)d_in[0];
  const float* cf = (const float*)d_in[1];
  const int* es = (const int*)d_in[2];
  const int* ed = (const int*)d_in[3];
  const float* ea = (const float*)d_in[4];
  const float* gn = (const float*)d_in[5];
  const float* bn = (const float*)d_in[6];
  const float* gc = (const float*)d_in[7];
  const float* bc = (const float*)d_in[8];
  const float* n_rel_w = (const float*)d_in[9];
  const float* n_rel_b = (const float*)d_in[10];
  const float* n_root_w = (const float*)d_in[11];
  const float* c_rel_w = (const float*)d_in[12];
  const float* c_rel_b = (const float*)d_in[13];
  const float* c_root_w = (const float*)d_in[14];
  float* out = (float*)d_out;
  float* ws = (float*)d_ws;

  float* ssum_node = ws;
  float* ssum_cstr = ws + 6400000;
  float* cnt_node = ws + 9600000;
  float* cnt_cstr = ws + 9700000;
  float* stats = ws + 9750000;
  float* ab = ws + 9750256;

  // Zero accumulators + stats (ws is re-poisoned to 0xAA before every call).
  hipMemsetAsync(d_ws, 0, 9750256u * sizeof(float), stream);

  bn_stats_k<<<512, 256, 0, stream>>>(vf, N_VAR, stats);
  bn_stats_k<<<512, 256, 0, stream>>>(cf, N_CSTR, stats + 128);
  bn_finalize_k<<<1, 128, 0, stream>>>(stats, gn, bn, gc, bc, ab);

  edge_scatter_k<<<8192, 256, 0, stream>>>(vf, cf, es, ed, ea, ab, ssum_node,
                                           ssum_cstr, cnt_node, cnt_cstr);

  out_k<<<1024, 256, 0, stream>>>(vf, ssum_node, cnt_node, ab, n_rel_w, n_rel_b,
                                  n_root_w, out, N_VAR);
  out_k<<<512, 256, 0, stream>>>(cf, ssum_cstr, cnt_cstr, ab + 128, c_rel_w,
                                 c_rel_b, c_root_w, out + 6400000, N_CSTR);
}